// Round 5
// baseline (64.258 us; speedup 1.0000x reference)
//
#include <hip/hip_runtime.h>
#include <hip/hip_bf16.h>

typedef __attribute__((ext_vector_type(8))) short short8;
typedef __attribute__((ext_vector_type(4))) float f32x4;

#define NROWS 8192
#define DCOLS 256
#define MARGIN 0.5f
#define NTILE 64   // 8192/128 tiles per dim
#define CHUNK 4    // j-tiles per block
#define NSEG 16    // max segments per row strip (64/4)

// --- Kernel 1: L2-normalize rows fp32 -> bf16, one wave per row ---
__global__ __launch_bounds__(256) void norm_kernel(const float* __restrict__ x,
                                                   unsigned short* __restrict__ e) {
    const int wave = threadIdx.x >> 6;
    const int lane = threadIdx.x & 63;
    const int row = blockIdx.x * 4 + wave;

    const float4 v = *reinterpret_cast<const float4*>(&x[row * DCOLS + lane * 4]);
    float ss = v.x * v.x + v.y * v.y + v.z * v.z + v.w * v.w;
#pragma unroll
    for (int off = 32; off >= 1; off >>= 1) ss += __shfl_down(ss, off);
    ss = __shfl(ss, 0);
    const float inv = 1.0f / fmaxf(sqrtf(ss), 1e-12f);

    __hip_bfloat16 h0 = __float2bfloat16(v.x * inv);
    __hip_bfloat16 h1 = __float2bfloat16(v.y * inv);
    __hip_bfloat16 h2 = __float2bfloat16(v.z * inv);
    __hip_bfloat16 h3 = __float2bfloat16(v.w * inv);
    ushort4 o;
    o.x = *reinterpret_cast<unsigned short*>(&h0);
    o.y = *reinterpret_cast<unsigned short*>(&h1);
    o.z = *reinterpret_cast<unsigned short*>(&h2);
    o.w = *reinterpret_cast<unsigned short*>(&h3);
    *reinterpret_cast<ushort4*>(&e[row * DCOLS + lane * 4]) = o;
}

// Stage one 128x64 bf16 B panel (16KB) for K-step ks of tile row group eBj.
// Linear LDS dest (wave-uniform base + lane*16); inverse-swizzled global source;
// matching XOR on the ds_read side (rule #21). 2 loads per wave x 8 waves.
__device__ __forceinline__ void stage_B(const unsigned short* __restrict__ eBj,
                                        unsigned short* Bbuf, int ks, int w, int l) {
#pragma unroll
    for (int i = 0; i < 2; ++i) {
        const int chb = i * 512 + w * 64;     // wave-uniform chunk base
        const int ch  = chb + l;              // per-lane chunk (0..1023)
        const int row = ch >> 3;              // 8 chunks (128B) per 64-col row
        const int cg  = (ch & 7) ^ (row & 7); // inverse swizzle
        __builtin_amdgcn_global_load_lds(
            (const __attribute__((address_space(1))) void*)(eBj + row * DCOLS + ks * 64 + cg * 8),
            (__attribute__((address_space(3))) void*)((char*)Bbuf + chb * 16),
            16, 0, 0);
    }
}

// --- Kernel 2: row-strip blocks. Block (seg, bi) computes tiles
// (bi, j0..j0+nj-1), j0 = bi + seg*CHUNK. A panel (128x256, 64KB) staged ONCE,
// B panels (128x64 per K-step) double-buffered: 2-phase pipeline, one barrier
// per step. 8 waves (2x4), wave tile 64x32, 16x16x32 bf16 MFMA.
__global__ __launch_bounds__(512, 2) void strip_kernel(const unsigned short* __restrict__ e,
                                                       float* __restrict__ part) {
    const int seg = blockIdx.x;               // 0..NSEG-1
    const int bi  = blockIdx.y;               // 0..NTILE-1
    const int slot = bi * NSEG + seg;
    const int j0  = bi + seg * CHUNK;
    const int nj  = min(CHUNK, NTILE - j0);
    if (nj <= 0) {                            // out of triangle: write 0, exit
        if (threadIdx.x == 0) part[slot] = 0.0f;
        return;
    }

    __shared__ unsigned short A_s[128 * 256];     // 64 KB, full K
    __shared__ unsigned short B_s[2][128 * 64];   // 2 x 16 KB
    __shared__ float red[8];

    const int t = threadIdx.x;
    const int l = t & 63;
    const int w = t >> 6;        // 0..7
    const int wr = w >> 2;       // wave row 0..1
    const int wc = w & 3;        // wave col 0..3
    const int lr = l & 15;       // fragment row index
    const int hk = l >> 4;       // k-group 0..3

    // --- prologue: stage full A panel (8 loads/wave) + first B K-step ---
    const unsigned short* eA = e + (size_t)bi * 128 * DCOLS;
#pragma unroll
    for (int i = 0; i < 8; ++i) {
        const int chb = i * 512 + w * 64;     // wave-uniform
        const int ch  = chb + l;              // 0..4095
        const int row = ch >> 5;              // 32 chunks (512B) per 256-col row
        const int cg  = (ch & 31) ^ (row & 7);
        __builtin_amdgcn_global_load_lds(
            (const __attribute__((address_space(1))) void*)(eA + row * DCOLS + cg * 8),
            (__attribute__((address_space(3))) void*)((char*)A_s + chb * 16),
            16, 0, 0);
    }
    stage_B(e + (size_t)j0 * 128 * DCOLS, B_s[0], 0, w, l);
    __syncthreads();

    f32x4 c[4][2];
#pragma unroll
    for (int m = 0; m < 4; ++m)
#pragma unroll
        for (int n = 0; n < 2; ++n)
            c[m][n] = (f32x4){0.f, 0.f, 0.f, 0.f};

    float local = 0.0f;
    const int nsteps = nj * 4;
    for (int s = 0; s < nsteps; ++s) {
        const int jt  = j0 + (s >> 2);
        const int ks  = s & 3;
        const int cur = s & 1;
        // issue next step's B staging (overlaps this step's compute)
        if (s + 1 < nsteps) {
            const int s2 = s + 1;
            stage_B(e + (size_t)(j0 + (s2 >> 2)) * 128 * DCOLS, B_s[s2 & 1], s2 & 3, w, l);
        }
        // compute: K-step ks of tile jt (2 substeps of K=32)
#pragma unroll
        for (int kk = 0; kk < 2; ++kk) {
            const int cgA = ks * 8 + kk * 4 + hk;   // 0..31 chunk within full K
            const int cgB = kk * 4 + hk;            // 0..7  chunk within K-step
            short8 a[4], b[2];
#pragma unroll
            for (int m = 0; m < 4; ++m) {
                const int r = wr * 64 + m * 16 + lr;
                a[m] = *reinterpret_cast<const short8*>(
                    (const char*)A_s + r * 512 + ((cgA ^ (r & 7)) << 4));
            }
#pragma unroll
            for (int n = 0; n < 2; ++n) {
                const int r = wc * 32 + n * 16 + lr;
                b[n] = *reinterpret_cast<const short8*>(
                    (const char*)B_s[cur] + r * 128 + ((cgB ^ (r & 7)) << 4));
            }
#pragma unroll
            for (int m = 0; m < 4; ++m)
#pragma unroll
                for (int n = 0; n < 2; ++n)
                    c[m][n] = __builtin_amdgcn_mfma_f32_16x16x32_bf16(a[m], b[n], c[m][n], 0, 0, 0);
        }
        // tile complete -> fused epilogue, reset accumulators
        if (ks == 3) {
            const int arow0 = bi * 128 + wr * 64;
            const int brow0 = jt * 128 + wc * 32;
#pragma unroll
            for (int m = 0; m < 4; ++m) {
#pragma unroll
                for (int n = 0; n < 2; ++n) {
#pragma unroll
                    for (int r = 0; r < 4; ++r) {
                        // C/D layout (m89-verified): col = lane&15, row = hk*4 + reg
                        const int gi = arow0 + m * 16 + hk * 4 + r;
                        const int gj = brow0 + n * 16 + lr;
                        const float v = c[m][n][r] - MARGIN;
                        local += (gi < gj) ? fmaxf(v, 0.0f) : 0.0f;
                    }
                    c[m][n] = (f32x4){0.f, 0.f, 0.f, 0.f};
                }
            }
        }
        __syncthreads();   // drains staged B + protects buffers
    }

    // --- block reduction: 512 threads -> one partial, no atomics ---
#pragma unroll
    for (int off = 32; off >= 1; off >>= 1) local += __shfl_down(local, off);
    if (l == 0) red[w] = local;
    __syncthreads();
    if (t == 0) {
        float s = 0.0f;
#pragma unroll
        for (int i = 0; i < 8; ++i) s += red[i];
        part[slot] = s;
    }
}

// --- Kernel 3: reduce 1024 partials, finalize ---
__global__ __launch_bounds__(1024) void fin_kernel(const float* __restrict__ part,
                                                   float* __restrict__ out) {
    __shared__ float red[16];
    const int t = threadIdx.x;
    float v = part[t];   // exactly NSEG*NTILE = 1024 slots
#pragma unroll
    for (int off = 32; off >= 1; off >>= 1) v += __shfl_down(v, off);
    if ((t & 63) == 0) red[t >> 6] = v;
    __syncthreads();
    if (t == 0) {
        float s = 0.0f;
#pragma unroll
        for (int i = 0; i < 16; ++i) s += red[i];
        out[0] = s / 33550336.0f;   // n*(n-1)/2 for n=8192
    }
}

extern "C" void kernel_launch(void* const* d_in, const int* in_sizes, int n_in,
                              void* d_out, int out_size, void* d_ws, size_t ws_size,
                              hipStream_t stream) {
    const float* x = (const float*)d_in[0];
    float* out = (float*)d_out;
    unsigned short* e = (unsigned short*)d_ws;
    float* part = (float*)((char*)d_ws + (size_t)NROWS * DCOLS * 2);

    norm_kernel<<<NROWS / 4, 256, 0, stream>>>(x, e);
    strip_kernel<<<dim3(NSEG, NTILE), 512, 0, stream>>>(e, part);
    fin_kernel<<<1, 1024, 0, stream>>>(part, out);
}

// Round 6
// 41.093 us; speedup vs baseline: 1.5637x; 1.5637x over previous
//
#include <hip/hip_runtime.h>
#include <hip/hip_bf16.h>

typedef __attribute__((ext_vector_type(8))) short short8;
typedef __attribute__((ext_vector_type(4))) float f32x4;

#define NROWS 8192
#define DCOLS 256
#define MARGIN 0.5f
#define NT 32          // 8192/256 supertiles per dim
#define NBLK 528       // NT*(NT+1)/2 upper-triangle tiles

// --- Kernel 1: L2-normalize rows fp32 -> bf16, one wave per row ---
__global__ __launch_bounds__(256) void norm_kernel(const float* __restrict__ x,
                                                   unsigned short* __restrict__ e) {
    const int wave = threadIdx.x >> 6;
    const int lane = threadIdx.x & 63;
    const int row = blockIdx.x * 4 + wave;

    const float4 v = *reinterpret_cast<const float4*>(&x[row * DCOLS + lane * 4]);
    float ss = v.x * v.x + v.y * v.y + v.z * v.z + v.w * v.w;
#pragma unroll
    for (int off = 32; off >= 1; off >>= 1) ss += __shfl_down(ss, off);
    ss = __shfl(ss, 0);
    const float inv = 1.0f / fmaxf(sqrtf(ss), 1e-12f);

    __hip_bfloat16 h0 = __float2bfloat16(v.x * inv);
    __hip_bfloat16 h1 = __float2bfloat16(v.y * inv);
    __hip_bfloat16 h2 = __float2bfloat16(v.z * inv);
    __hip_bfloat16 h3 = __float2bfloat16(v.w * inv);
    ushort4 o;
    o.x = *reinterpret_cast<unsigned short*>(&h0);
    o.y = *reinterpret_cast<unsigned short*>(&h1);
    o.z = *reinterpret_cast<unsigned short*>(&h2);
    o.w = *reinterpret_cast<unsigned short*>(&h3);
    *reinterpret_cast<ushort4*>(&e[row * DCOLS + lane * 4]) = o;
}

// Stage one K-tile (BK=32): A panel 256x32 + B panel 256x32 (16KB each) into
// ring buffers. LDS layout: 128 physical rows x 128B; logical row r at phys row
// r>>1, 16B slot s = ((r&1)*4 + cg) ^ ((r>>1)&7)  [2-way-free XOR swizzle].
// global_load_lds needs linear LDS dest (wave-uniform base + lane*16), so the
// swizzle is applied by inverse-permuting the GLOBAL source address (rule #21).
// 4 loads per thread per K-tile (2 A + 2 B) -> vmcnt granularity = 4/K-tile.
__device__ __forceinline__ void stage_ktile(const unsigned short* __restrict__ eA,
                                            const unsigned short* __restrict__ eB,
                                            unsigned short* Ab, unsigned short* Bb,
                                            int k0, int w, int l) {
#pragma unroll
    for (int i = 0; i < 2; ++i) {
        const int chb = i * 512 + w * 64;   // wave-uniform chunk base
        const int ch  = chb + l;            // 0..1023 (16B chunks)
        const int pr  = ch >> 3;            // physical row 0..127
        const int v   = (ch & 7) ^ (pr & 7);
        const int r   = pr * 2 + (v >> 2);  // logical row 0..255
        const int go  = r * DCOLS + k0 + (v & 3) * 8;
        __builtin_amdgcn_global_load_lds(
            (const __attribute__((address_space(1))) void*)(eA + go),
            (__attribute__((address_space(3))) void*)((char*)Ab + chb * 16), 16, 0, 0);
        __builtin_amdgcn_global_load_lds(
            (const __attribute__((address_space(1))) void*)(eB + go),
            (__attribute__((address_space(3))) void*)((char*)Bb + chb * 16), 16, 0, 0);
    }
}

// --- Kernel 2: 256x256 sim supertiles, compact triangular grid, counted-vmcnt
// ring-4 pipeline (T3+T4): per K-tile {vmcnt(8); s_barrier; stage(kt+3);
// ds_read+MFMA}. Loads stay in flight across barriers; vmcnt never drains to 0
// in steady state. 8 waves (2Mx4N), wave tile 128x64 = acc[8][4] of 16x16x32.
__global__ __launch_bounds__(512, 2) void tile_kernel(const unsigned short* __restrict__ e,
                                                      float* __restrict__ part) {
    // XCD-aware bijective swizzle (NBLK = 528 = 8*66)
    const int orig = blockIdx.x;
    const int t0 = (orig & 7) * 66 + (orig >> 3);
    // decode t0 -> (bi,bj), bi<=bj, over NT x NT upper triangle
    int bi = (int)((65.0 - sqrt(4225.0 - 8.0 * (double)t0)) * 0.5);
    if (bi < 0) bi = 0;
    if (bi > NT - 1) bi = NT - 1;
#define CUM(b) (((b) * (65 - (b))) >> 1)
    while (bi + 1 <= NT - 1 && CUM(bi + 1) <= t0) ++bi;
    while (bi > 0 && CUM(bi) > t0) --bi;
    const int bj = bi + (t0 - CUM(bi));
#undef CUM

    __shared__ unsigned short LA[4][8192];   // ring of 4 A K-tiles, 16KB each
    __shared__ unsigned short LB[4][8192];   // ring of 4 B K-tiles
    __shared__ float red[8];

    const int t = threadIdx.x;
    const int l = t & 63;
    const int w = t >> 6;        // 0..7
    const int wm = w >> 2;       // wave M 0..1  (wave tile 128 rows)
    const int wn = w & 3;        // wave N 0..3  (wave tile 64 cols)
    const int lr = l & 15;
    const int hk = l >> 4;

    const unsigned short* eA = e + (size_t)bi * 256 * DCOLS;
    const unsigned short* eB = e + (size_t)bj * 256 * DCOLS;

    f32x4 acc[8][4];
#pragma unroll
    for (int m = 0; m < 8; ++m)
#pragma unroll
        for (int n = 0; n < 4; ++n)
            acc[m][n] = (f32x4){0.f, 0.f, 0.f, 0.f};

    // prologue: prefetch K-tiles 0,1,2 (12 outstanding loads/thread)
    stage_ktile(eA, eB, LA[0], LB[0], 0, w, l);
    stage_ktile(eA, eB, LA[1], LB[1], 32, w, l);
    stage_ktile(eA, eB, LA[2], LB[2], 64, w, l);

#pragma unroll
    for (int kt = 0; kt < 8; ++kt) {
        // wait until THIS K-tile's 4 loads (oldest) have landed — counted, not 0
        if (kt <= 5)      asm volatile("s_waitcnt vmcnt(8)" ::: "memory");
        else if (kt == 6) asm volatile("s_waitcnt vmcnt(4)" ::: "memory");
        else              asm volatile("s_waitcnt vmcnt(0)" ::: "memory");
        // raw barrier (NOT __syncthreads: avoids compiler's vmcnt(0) drain).
        // All waves did their own vmcnt wait -> K-tile kt fully visible; also
        // separates prev iter's ds_reads (completed: MFMAs consumed them) from
        // the stage below that overwrites buffer (kt+3)&3 = (kt-1)&3.
        __builtin_amdgcn_s_barrier();
        if (kt + 3 < 8)
            stage_ktile(eA, eB, LA[(kt + 3) & 3], LB[(kt + 3) & 3], (kt + 3) * 32, w, l);

        const unsigned short* Ab = (const unsigned short*)LA[kt & 3];
        const unsigned short* Bb = (const unsigned short*)LB[kt & 3];
        short8 af[8], bf[4];
#pragma unroll
        for (int m = 0; m < 8; ++m) {
            const int r = wm * 128 + m * 16 + lr;
            const int pr = r >> 1;
            af[m] = *reinterpret_cast<const short8*>(
                (const char*)Ab + (pr << 7) + ((((r & 1) * 4 + hk) ^ (pr & 7)) << 4));
        }
#pragma unroll
        for (int n = 0; n < 4; ++n) {
            const int r = wn * 64 + n * 16 + lr;
            const int pr = r >> 1;
            bf[n] = *reinterpret_cast<const short8*>(
                (const char*)Bb + (pr << 7) + ((((r & 1) * 4 + hk) ^ (pr & 7)) << 4));
        }
        __builtin_amdgcn_s_setprio(1);
#pragma unroll
        for (int m = 0; m < 8; ++m)
#pragma unroll
            for (int n = 0; n < 4; ++n)
                acc[m][n] = __builtin_amdgcn_mfma_f32_16x16x32_bf16(af[m], bf[n], acc[m][n], 0, 0, 0);
        __builtin_amdgcn_s_setprio(0);
    }

    // --- epilogue: relu(sim - margin), strict upper-triangle mask, reduce ---
    // C/D layout (m89-verified): col = lane&15, row = (lane>>4)*4 + reg.
    const int gi0 = bi * 256 + wm * 128;
    const int gj0 = bj * 256 + wn * 64;
    float local = 0.0f;
#pragma unroll
    for (int m = 0; m < 8; ++m) {
#pragma unroll
        for (int n = 0; n < 4; ++n) {
#pragma unroll
            for (int r = 0; r < 4; ++r) {
                const int gi = gi0 + m * 16 + hk * 4 + r;
                const int gj = gj0 + n * 16 + lr;
                const float v = acc[m][n][r] - MARGIN;
                local += (gi < gj) ? fmaxf(v, 0.0f) : 0.0f;
            }
        }
    }
#pragma unroll
    for (int off = 32; off >= 1; off >>= 1) local += __shfl_down(local, off);
    if (l == 0) red[w] = local;
    __syncthreads();
    if (t == 0) {
        float s = 0.0f;
#pragma unroll
        for (int i = 0; i < 8; ++i) s += red[i];
        part[orig] = s;
    }
}

// --- Kernel 3: reduce NBLK partials, finalize ---
__global__ __launch_bounds__(512) void fin_kernel(const float* __restrict__ part,
                                                  float* __restrict__ out) {
    __shared__ float red[8];
    const int t = threadIdx.x;
    float v = part[t] + (t < NBLK - 512 ? part[512 + t] : 0.0f);
#pragma unroll
    for (int off = 32; off >= 1; off >>= 1) v += __shfl_down(v, off);
    if ((t & 63) == 0) red[t >> 6] = v;
    __syncthreads();
    if (t == 0) {
        float s = 0.0f;
#pragma unroll
        for (int i = 0; i < 8; ++i) s += red[i];
        out[0] = s / 33550336.0f;   // n*(n-1)/2 for n=8192
    }
}

extern "C" void kernel_launch(void* const* d_in, const int* in_sizes, int n_in,
                              void* d_out, int out_size, void* d_ws, size_t ws_size,
                              hipStream_t stream) {
    const float* x = (const float*)d_in[0];
    float* out = (float*)d_out;
    unsigned short* e = (unsigned short*)d_ws;
    float* part = (float*)((char*)d_ws + (size_t)NROWS * DCOLS * 2);

    norm_kernel<<<NROWS / 4, 256, 0, stream>>>(x, e);
    tile_kernel<<<NBLK, 512, 0, stream>>>(e, part);
    fin_kernel<<<1, 512, 0, stream>>>(part, out);
}